// Round 10
// baseline (829.236 us; speedup 1.0000x reference)
//
#include <hip/hip_runtime.h>
#include <hip/hip_bf16.h>
#include <math.h>

#define NE 6

typedef __bf16 bf16x8 __attribute__((ext_vector_type(8)));
typedef float f32x4 __attribute__((ext_vector_type(4)));
typedef short short8 __attribute__((ext_vector_type(8)));

// byte-offset swizzle within a [64 rows][64 k] bf16 LDS tile (row stride 128B)
#define SWZ(row, kbyte) (((row) * 128) + ((kbyte) ^ (((row) & 7) << 4)))

static __device__ __forceinline__ short f2bf(float f) {
    __hip_bfloat16 h = __float2bfloat16(f);
    return __builtin_bit_cast(short, h);
}

static __device__ __forceinline__ float bf2f(short s) {
    return __bfloat162float(__builtin_bit_cast(__hip_bfloat16, s));
}

// ---------------- RoPE tables ----------------
__global__ void rope_tables(float* __restrict__ ct, float* __restrict__ st) {
    int id = blockIdx.x * 256 + threadIdx.x;   // 2048*16
    if (id >= 2048 * 16) return;
    int s = id >> 4, f = id & 15;
    float invf = expf(-logf(10000.0f) * (float)f / 16.0f);
    float ang = (float)s * invf;
    ct[id] = cosf(ang);
    st[id] = sinf(ang);
}

// ---------------- RMSNorm (fp32 out) ----------------
__global__ void rmsnorm_k(const float* __restrict__ x, const float* __restrict__ w,
                          float* __restrict__ o) {
    __shared__ float red[256];
    int n = blockIdx.x, t = threadIdx.x;
    float v = x[n * 256 + t];
    red[t] = v * v;
    __syncthreads();
    for (int s = 128; s > 0; s >>= 1) {
        if (t < s) red[t] += red[t + s];
        __syncthreads();
    }
    float rms = rsqrtf(red[0] / 256.0f + 1e-6f);
    o[n * 256 + t] = v * rms * w[t];
}

// ---------------- RMSNorm (fp32 + bf16 out) ----------------
__global__ void rmsnorm_both(const float* __restrict__ x, const float* __restrict__ w,
                             float* __restrict__ o, short* __restrict__ obf) {
    __shared__ float red[256];
    int n = blockIdx.x, t = threadIdx.x;
    float v = x[n * 256 + t];
    red[t] = v * v;
    __syncthreads();
    for (int s = 128; s > 0; s >>= 1) {
        if (t < s) red[t] += red[t + s];
        __syncthreads();
    }
    float rms = rsqrtf(red[0] / 256.0f + 1e-6f);
    float val = v * rms * w[t];
    o[n * 256 + t] = val;
    obf[n * 256 + t] = f2bf(val);
}

// ---------------- tiled transpose + fp32->bf16: src[R][C] -> dst[C][R] ----------------
__global__ __launch_bounds__(256) void transcvt_k(const float* __restrict__ src,
                                                  short* __restrict__ dst, int R, int C) {
    __shared__ short tile[32][33];
    const float* s = src + (size_t)blockIdx.z * R * C;
    short* d = dst + (size_t)blockIdx.z * R * C;
    int t = threadIdx.x;
    int c0 = blockIdx.x * 32, r0 = blockIdx.y * 32;
    int ci = t & 31, ri0 = t >> 5;
#pragma unroll
    for (int it = 0; it < 4; it++) {
        int ri = ri0 + it * 8;
        tile[ri][ci] = f2bf(s[(size_t)(r0 + ri) * C + c0 + ci]);
    }
    __syncthreads();
#pragma unroll
    for (int it = 0; it < 4; it++) {
        int rj = ri0 + it * 8;
        d[(size_t)(c0 + rj) * R + r0 + ci] = tile[ci][rj];
    }
}

// ---------------- QKV GEMM (fp32, unchanged): scatter to Q/K/V (B,H,S,D) ----------------
__global__ __launch_bounds__(256) void gemm_qkv(const float* __restrict__ A,
                                                const float* __restrict__ W,
                                                float* __restrict__ Q, float* __restrict__ Kq,
                                                float* __restrict__ V) {
    __shared__ float As[16][64];
    __shared__ float Bs[16][64];
    int t = threadIdx.x;
    int m0 = blockIdx.y * 64, n0 = blockIdx.x * 64;
    float acc[4][4] = {};
    int am = t >> 2, ak = (t & 3) * 4;
    int bk = t >> 4, bn = (t & 15) * 4;
    int tm = (t & 15) * 4, tn = (t >> 4) * 4;
    for (int k0 = 0; k0 < 256; k0 += 16) {
        float4 av = *(const float4*)&A[(m0 + am) * 256 + k0 + ak];
        As[ak + 0][am] = av.x; As[ak + 1][am] = av.y; As[ak + 2][am] = av.z; As[ak + 3][am] = av.w;
        float4 bv = *(const float4*)&W[(k0 + bk) * 768 + n0 + bn];
        *(float4*)&Bs[bk][bn] = bv;
        __syncthreads();
#pragma unroll
        for (int kk = 0; kk < 16; kk++) {
            float4 a4 = *(float4*)&As[kk][tm];
            float4 b4 = *(float4*)&Bs[kk][tn];
            float a[4] = {a4.x, a4.y, a4.z, a4.w};
            float b[4] = {b4.x, b4.y, b4.z, b4.w};
#pragma unroll
            for (int i = 0; i < 4; i++)
#pragma unroll
                for (int j = 0; j < 4; j++) acc[i][j] += a[i] * b[j];
        }
        __syncthreads();
    }
    int part = n0 >> 8;
    float* dst = part == 0 ? Q : (part == 1 ? Kq : V);
#pragma unroll
    for (int i = 0; i < 4; i++) {
        int rowi = m0 + tm + i;
        int b = rowi >> 11, s = rowi & 2047;
#pragma unroll
        for (int j = 0; j < 4; j++) {
            int c = n0 + tn + j;
            int e = c & 255, h = e >> 5, d = e & 31;
            dst[(((size_t)(b * 8 + h)) * 2048 + s) * 32 + d] = acc[i][j];
        }
    }
}

// ---------------- RoPE in place on Q and K ----------------
__global__ void rope_k(float* __restrict__ Q, float* __restrict__ Kq,
                       const float* __restrict__ ct, const float* __restrict__ st) {
    int id = blockIdx.x * 256 + threadIdx.x;  // 32*2048*16
    if (id >= 32 * 2048 * 16) return;
    int i = id & 15;
    int s = (id >> 4) & 2047;
    int bh = id >> 15;
    int base = (bh * 2048 + s) * 32 + 2 * i;
    int j0 = (2 * i) & 15;
    float c0 = ct[s * 16 + j0], s0 = st[s * 16 + j0];
    float c1 = ct[s * 16 + j0 + 1], s1 = st[s * 16 + j0 + 1];
    float2 q = *(float2*)&Q[base];
    float2 k = *(float2*)&Kq[base];
    float2 qo, ko;
    qo.x = q.x * c0 - q.y * s0;
    qo.y = q.y * c1 + q.x * s1;
    ko.x = k.x * c0 - k.y * s0;
    ko.y = k.y * c1 + k.x * s1;
    *(float2*)&Q[base] = qo;
    *(float2*)&Kq[base] = ko;
}

// ---------------- Flash attention: 4 lanes per TWO query rows (r, r+64), 128 rows/block ----
__global__ __launch_bounds__(256) void attn_k(const float* __restrict__ Q,
                                              const float* __restrict__ Kg,
                                              const float* __restrict__ Vg,
                                              float* __restrict__ ctx) {
    __shared__ float4 Kl[64][8];
    __shared__ float4 Vl[64][8];
    int bh = blockIdx.x;
    int qt = gridDim.y - 1 - blockIdx.y;   // longest blocks launch first; qt in 0..15
    int t = threadIdx.x;
    int sub = t & 3;            // which 8-dim slice of D
    int row0 = qt * 128 + (t >> 2);
    int row1 = row0 + 64;
    const float4* Qb = (const float4*)(Q + (size_t)bh * 2048 * 32);
    const float4* Kb = (const float4*)(Kg + (size_t)bh * 2048 * 32);
    const float4* Vb = (const float4*)(Vg + (size_t)bh * 2048 * 32);
    float4 qa0 = Qb[row0 * 8 + sub * 2];
    float4 qa1 = Qb[row0 * 8 + sub * 2 + 1];
    float4 qb0 = Qb[row1 * 8 + sub * 2];
    float4 qb1 = Qb[row1 * 8 + sub * 2 + 1];
    float4 oa0 = {}, oa1 = {}, ob0 = {}, ob1 = {};
    float ma = -1e30f, la = 0.f, mb = -1e30f, lb = 0.f;
    const float scale = 0.17677669529663687f;  // 1/sqrt(32)
    int ntile = qt * 2 + 2;
    float4* Klf = &Kl[0][0];
    float4* Vlf = &Vl[0][0];
    for (int kt = 0; kt < ntile; kt++) {
        int kbase = kt * 64;
        Klf[t] = Kb[kbase * 8 + t];
        Klf[t + 256] = Kb[kbase * 8 + t + 256];
        Vlf[t] = Vb[kbase * 8 + t];
        Vlf[t + 256] = Vb[kbase * 8 + t + 256];
        __syncthreads();
        int ja = row0 - kbase + 1;          // #keys valid for row A in this tile
        if (ja > 64) ja = 64;
        if (ja < 0) ja = 0;
        int jb = row1 - kbase + 1;          // row B always has >=1 valid key while kt<ntile
        if (jb > 64) jb = 64;
        // register double-buffer: preload key j+1 while computing key j
        float4 k0 = Kl[0][sub * 2], k1 = Kl[0][sub * 2 + 1];
        float4 v0 = Vl[0][sub * 2], v1 = Vl[0][sub * 2 + 1];
        for (int j = 0; j < jb; j++) {
            int jn = (j + 1 < 64) ? j + 1 : 63;
            float4 nk0 = Kl[jn][sub * 2], nk1 = Kl[jn][sub * 2 + 1];
            float4 nv0 = Vl[jn][sub * 2], nv1 = Vl[jn][sub * 2 + 1];
            float sA = qa0.x * k0.x + qa0.y * k0.y + qa0.z * k0.z + qa0.w * k0.w +
                       qa1.x * k1.x + qa1.y * k1.y + qa1.z * k1.z + qa1.w * k1.w;
            float sB = qb0.x * k0.x + qb0.y * k0.y + qb0.z * k0.z + qb0.w * k0.w +
                       qb1.x * k1.x + qb1.y * k1.y + qb1.z * k1.z + qb1.w * k1.w;
            sA += __shfl_xor(sA, 1);
            sA += __shfl_xor(sA, 2);
            sB += __shfl_xor(sB, 1);
            sB += __shfl_xor(sB, 2);
            sA *= scale;
            sB *= scale;
            if (j < ja) {
                if (sA > ma) {
                    float r = __expf(ma - sA);
                    oa0.x *= r; oa0.y *= r; oa0.z *= r; oa0.w *= r;
                    oa1.x *= r; oa1.y *= r; oa1.z *= r; oa1.w *= r;
                    la *= r;
                    ma = sA;
                }
                float p = __expf(sA - ma);
                la += p;
                oa0.x += p * v0.x; oa0.y += p * v0.y; oa0.z += p * v0.z; oa0.w += p * v0.w;
                oa1.x += p * v1.x; oa1.y += p * v1.y; oa1.z += p * v1.z; oa1.w += p * v1.w;
            }
            if (sB > mb) {
                float r = __expf(mb - sB);
                ob0.x *= r; ob0.y *= r; ob0.z *= r; ob0.w *= r;
                ob1.x *= r; ob1.y *= r; ob1.z *= r; ob1.w *= r;
                lb *= r;
                mb = sB;
            }
            float pB = __expf(sB - mb);
            lb += pB;
            ob0.x += pB * v0.x; ob0.y += pB * v0.y; ob0.z += pB * v0.z; ob0.w += pB * v0.w;
            ob1.x += pB * v1.x; ob1.y += pB * v1.y; ob1.z += pB * v1.z; ob1.w += pB * v1.w;
            k0 = nk0; k1 = nk1; v0 = nv0; v1 = nv1;
        }
        __syncthreads();
    }
    int b = bh >> 3, h = bh & 7;
    float invla = 1.f / la;
    float4* cpa = (float4*)(ctx + ((size_t)(b * 2048 + row0)) * 256 + h * 32 + sub * 8);
    oa0.x *= invla; oa0.y *= invla; oa0.z *= invla; oa0.w *= invla;
    oa1.x *= invla; oa1.y *= invla; oa1.z *= invla; oa1.w *= invla;
    cpa[0] = oa0;
    cpa[1] = oa1;
    float invlb = 1.f / lb;
    float4* cpb = (float4*)(ctx + ((size_t)(b * 2048 + row1)) * 256 + h * 32 + sub * 8);
    ob0.x *= invlb; ob0.y *= invlb; ob0.z *= invlb; ob0.w *= invlb;
    ob1.x *= invlb; ob1.y *= invlb; ob1.z *= invlb; ob1.w *= invlb;
    cpb[0] = ob0;
    cpb[1] = ob1;
}

// ---------------- out projection + residual (fp32, unchanged) ----------------
__global__ __launch_bounds__(256) void gemm_out(const float* __restrict__ A,
                                                const float* __restrict__ W,
                                                const float* __restrict__ xres,
                                                float* __restrict__ x2) {
    __shared__ float As[16][64];
    __shared__ float Bs[16][64];
    int t = threadIdx.x;
    int m0 = blockIdx.y * 64, n0 = blockIdx.x * 64;
    float acc[4][4] = {};
    int am = t >> 2, ak = (t & 3) * 4;
    int bk = t >> 4, bn = (t & 15) * 4;
    int tm = (t & 15) * 4, tn = (t >> 4) * 4;
    for (int k0 = 0; k0 < 256; k0 += 16) {
        float4 av = *(const float4*)&A[(m0 + am) * 256 + k0 + ak];
        As[ak + 0][am] = av.x; As[ak + 1][am] = av.y; As[ak + 2][am] = av.z; As[ak + 3][am] = av.w;
        float4 bv = *(const float4*)&W[(k0 + bk) * 256 + n0 + bn];
        *(float4*)&Bs[bk][bn] = bv;
        __syncthreads();
#pragma unroll
        for (int kk = 0; kk < 16; kk++) {
            float4 a4 = *(float4*)&As[kk][tm];
            float4 b4 = *(float4*)&Bs[kk][tn];
            float a[4] = {a4.x, a4.y, a4.z, a4.w};
            float b[4] = {b4.x, b4.y, b4.z, b4.w};
#pragma unroll
            for (int i = 0; i < 4; i++)
#pragma unroll
                for (int j = 0; j < 4; j++) acc[i][j] += a[i] * b[j];
        }
        __syncthreads();
    }
#pragma unroll
    for (int i = 0; i < 4; i++) {
        int rowi = m0 + tm + i;
#pragma unroll
        for (int j = 0; j < 4; j++) {
            int c = n0 + tn + j;
            x2[rowi * 256 + c] = acc[i][j] + xres[rowi * 256 + c];
        }
    }
}

// ---------------- gate: logits, softmax, top-2, importance/counts ----------------
__global__ void gate_k(const float* __restrict__ xn2, const float* __restrict__ gw,
                       int* __restrict__ idx, float* __restrict__ wts,
                       int* __restrict__ cnt, float* __restrict__ imp) {
    __shared__ float simp[NE];
    __shared__ int scnt[NE];
    int t = threadIdx.x;
    int n = blockIdx.x * 256 + t;
    if (t < NE) { simp[t] = 0.f; scnt[t] = 0; }
    __syncthreads();
    float lg[NE] = {0, 0, 0, 0, 0, 0};
    for (int k = 0; k < 256; k++) {
        float xv = xn2[n * 256 + k];
#pragma unroll
        for (int e = 0; e < NE; e++) lg[e] += xv * gw[k * NE + e];
    }
    float mx = lg[0];
#pragma unroll
    for (int e = 1; e < NE; e++) mx = fmaxf(mx, lg[e]);
    float p[NE], se = 0.f;
#pragma unroll
    for (int e = 0; e < NE; e++) { p[e] = expf(lg[e] - mx); se += p[e]; }
    float inv = 1.f / se;
#pragma unroll
    for (int e = 0; e < NE; e++) p[e] *= inv;
    int i1 = 0; float v1 = p[0];
#pragma unroll
    for (int e = 1; e < NE; e++) if (p[e] > v1) { v1 = p[e]; i1 = e; }
    int i2 = -1; float v2 = -1.f;
#pragma unroll
    for (int e = 0; e < NE; e++) if (e != i1 && p[e] > v2) { v2 = p[e]; i2 = e; }
    float e2v = expf(v2 - v1);
    float w1 = 1.f / (1.f + e2v);
    float w2 = e2v / (1.f + e2v);
    idx[n * 2] = i1; idx[n * 2 + 1] = i2;
    wts[n * 2] = w1; wts[n * 2 + 1] = w2;
#pragma unroll
    for (int e = 0; e < NE; e++) atomicAdd(&simp[e], p[e]);
    atomicAdd(&scnt[i1], 1);
    atomicAdd(&scnt[i2], 1);
    __syncthreads();
    if (t < NE) {
        atomicAdd(&imp[t], simp[t]);
        atomicAdd(&cnt[t], scnt[t]);
    }
}

// ---------------- prefix sums + aux loss ----------------
__global__ void prefix_k(const int* __restrict__ cnt, const float* __restrict__ imp,
                         int* __restrict__ offs, int* __restrict__ cur,
                         float* __restrict__ auxout) {
    if (threadIdx.x == 0) {
        int o = 0;
        float a = 0.f;
        for (int e = 0; e < NE; e++) {
            offs[e] = o;
            cur[e] = o;
            o += cnt[e];
            a += imp[e] * (float)cnt[e];
        }
        auxout[0] = 6.0f * a / (8192.0f * 8192.0f);
    }
}

// ---------------- scatter token slots into expert buckets ----------------
__global__ void scatter_k(const int* __restrict__ idx, int* __restrict__ cur,
                          int* __restrict__ ltok, int* __restrict__ slotp) {
    int n = blockIdx.x * 256 + threadIdx.x;
#pragma unroll
    for (int s = 0; s < 2; s++) {
        int e = idx[n * 2 + s];
        int pos = atomicAdd(&cur[e], 1);
        ltok[pos] = n;
        slotp[n * 2 + s] = pos;
    }
}

// ---------------- MFMA expert GEMM 1: H = silu(A@Wg)*(A@Wu), gathered rows ----------------
// A: xn2 bf16 [8192][256] gathered via ltok; B: WgT/WuT bf16 [e][768][256] (n-major)
__global__ __launch_bounds__(256) void mfma_moe1(const short* __restrict__ xnbf,
                                                 const short* __restrict__ WgT,
                                                 const short* __restrict__ WuT,
                                                 const int* __restrict__ cnt,
                                                 const int* __restrict__ offs,
                                                 const int* __restrict__ ltok,
                                                 short* __restrict__ Hbuf) {
    int e = blockIdx.z;
    int Me = cnt[e];
    int m0 = blockIdx.y * 64;
    if (m0 >= Me) return;
    int off = offs[e];
    __shared__ short As[4096], Bg[4096], Bu[4096];
    __shared__ int stok[64];
    int t = threadIdx.x;
    if (t < 64) stok[t] = (m0 + t < Me) ? ltok[off + m0 + t] : ltok[off];
    __syncthreads();
    int n0 = blockIdx.x * 64;
    const short* WgE = WgT + (size_t)e * 768 * 256;
    const short* WuE = WuT + (size_t)e * 768 * 256;
    int lane = t & 63, wid = t >> 6, wr = wid >> 1, wc = wid & 1;
    int l15 = lane & 15, lh = lane >> 4;
    int r = t >> 3, k8 = (t & 7) * 8, kb8 = (t & 7) * 16;
    char* AsC = (char*)As; char* BgC = (char*)Bg; char* BuC = (char*)Bu;
    f32x4 accg[2][2] = {}, accu[2][2] = {};
    for (int k0 = 0; k0 < 256; k0 += 64) {
        short8 av0 = *(const short8*)&xnbf[(size_t)stok[r] * 256 + k0 + k8];
        short8 av1 = *(const short8*)&xnbf[(size_t)stok[r + 32] * 256 + k0 + k8];
        short8 gv0 = *(const short8*)&WgE[(size_t)(n0 + r) * 256 + k0 + k8];
        short8 gv1 = *(const short8*)&WgE[(size_t)(n0 + r + 32) * 256 + k0 + k8];
        short8 uv0 = *(const short8*)&WuE[(size_t)(n0 + r) * 256 + k0 + k8];
        short8 uv1 = *(const short8*)&WuE[(size_t)(n0 + r + 32) * 256 + k0 + k8];
        *(short8*)(AsC + SWZ(r, kb8)) = av0;
        *(short8*)(AsC + SWZ(r + 32, kb8)) = av1;
        *(short8*)(BgC + SWZ(r, kb8)) = gv0;
        *(short8*)(BgC + SWZ(r + 32, kb8)) = gv1;
        *(short8*)(BuC + SWZ(r, kb8)) = uv0;
        *(short8*)(BuC + SWZ(r + 32, kb8)) = uv1;
        __syncthreads();
#pragma unroll
        for (int kk = 0; kk < 2; kk++) {
            int kb = kk * 64 + lh * 16;
            bf16x8 a[2], bg[2], bu[2];
#pragma unroll
            for (int i = 0; i < 2; i++) {
                a[i]  = *(const bf16x8*)(AsC + SWZ(wr * 32 + i * 16 + l15, kb));
                bg[i] = *(const bf16x8*)(BgC + SWZ(wc * 32 + i * 16 + l15, kb));
                bu[i] = *(const bf16x8*)(BuC + SWZ(wc * 32 + i * 16 + l15, kb));
            }
#pragma unroll
            for (int mi = 0; mi < 2; mi++)
#pragma unroll
                for (int ni = 0; ni < 2; ni++) {
                    accg[mi][ni] = __builtin_amdgcn_mfma_f32_16x16x32_bf16(a[mi], bg[ni], accg[mi][ni], 0, 0, 0);
                    accu[mi][ni] = __builtin_amdgcn_mfma_f32_16x16x32_bf16(a[mi], bu[ni], accu[mi][ni], 0, 0, 0);
                }
        }
        __syncthreads();
    }
#pragma unroll
    for (int mi = 0; mi < 2; mi++)
#pragma unroll
        for (int j = 0; j < 4; j++) {
            int m = m0 + wr * 32 + mi * 16 + lh * 4 + j;
            if (m < Me) {
                size_t rp = (size_t)(off + m) * 768;
#pragma unroll
                for (int ni = 0; ni < 2; ni++) {
                    int c = n0 + wc * 32 + ni * 16 + l15;
                    float g = accg[mi][ni][j], u = accu[mi][ni][j];
                    Hbuf[rp + c] = f2bf(g / (1.f + __expf(-g)) * u);
                }
            }
        }
}

// ---------------- MFMA expert GEMM 2: Y = H @ Wd ----------------
// A: Hbuf bf16 [16384][768]; B: WdT bf16 [e][256][768] (n-major)
__global__ __launch_bounds__(256) void mfma_moe2(const short* __restrict__ Hbuf,
                                                 const short* __restrict__ WdT,
                                                 const int* __restrict__ cnt,
                                                 const int* __restrict__ offs,
                                                 short* __restrict__ Y) {
    int e = blockIdx.z;
    int Me = cnt[e];
    int m0 = blockIdx.y * 64;
    if (m0 >= Me) return;
    int off = offs[e];
    __shared__ short As[4096], Bs[4096];
    int t = threadIdx.x;
    int n0 = blockIdx.x * 64;
    const short* WdE = WdT + (size_t)e * 256 * 768;
    int lane = t & 63, wid = t >> 6, wr = wid >> 1, wc = wid & 1;
    int l15 = lane & 15, lh = lane >> 4;
    int r = t >> 3, k8 = (t & 7) * 8, kb8 = (t & 7) * 16;
    int ar0 = off + m0 + r;       if (ar0 > 16383) ar0 = 16383;
    int ar1 = off + m0 + r + 32;  if (ar1 > 16383) ar1 = 16383;
    char* AsC = (char*)As; char* BsC = (char*)Bs;
    f32x4 acc[2][2] = {};
    for (int k0 = 0; k0 < 768; k0 += 64) {
        short8 av0 = *(const short8*)&Hbuf[(size_t)ar0 * 768 + k0 + k8];
        short8 av1 = *(const short8*)&Hbuf[(size_t)ar1 * 768 + k0 + k8];
        short8 bv0 = *(const short8*)&WdE[(size_t)(n0 + r) * 768 + k0 + k8];
        short8 bv1 = *(const short8*)&WdE[(size_t)(n0 + r + 32) * 768 + k0 + k8];
        *(short8*)(AsC + SWZ(r, kb8)) = av0;
        *(short8*)(AsC + SWZ(r + 32, kb8)) = av1;
        *(short8*)(BsC + SWZ(r, kb8)) = bv0;
        *(short8*)(BsC + SWZ(r + 32, kb8)) = bv1;
        __syncthreads();
#pragma unroll
        for (int kk = 0; kk < 2; kk++) {
            int kb = kk * 64 + lh * 16;
            bf16x8 a[2], b[2];
#pragma unroll
            for (int i = 0; i < 2; i++) {
                a[i] = *(const bf16x8*)(AsC + SWZ(wr * 32 + i * 16 + l15, kb));
                b[i] = *(const bf16x8*)(BsC + SWZ(wc * 32 + i * 16 + l15, kb));
            }
#pragma unroll
            for (int mi = 0; mi < 2; mi++)
#pragma unroll
                for (int ni = 0; ni < 2; ni++)
                    acc[mi][ni] = __builtin_amdgcn_mfma_f32_16x16x32_bf16(a[mi], b[ni], acc[mi][ni], 0, 0, 0);
        }
        __syncthreads();
    }
#pragma unroll
    for (int mi = 0; mi < 2; mi++)
#pragma unroll
        for (int j = 0; j < 4; j++) {
            int m = m0 + wr * 32 + mi * 16 + lh * 4 + j;
            if (m < Me) {
                size_t rp = (size_t)(off + m) * 256;
#pragma unroll
                for (int ni = 0; ni < 2; ni++) {
                    int c = n0 + wc * 32 + ni * 16 + l15;
                    Y[rp + c] = f2bf(acc[mi][ni][j]);
                }
            }
        }
}

// ---------------- final combine: out = x2 + w0*Y[p0] + w1*Y[p1] ----------------
__global__ void combine_k(const float* __restrict__ x2, const short* __restrict__ Y,
                          const int* __restrict__ slotp, const float* __restrict__ wts,
                          float* __restrict__ out) {
    int n = blockIdx.x, t = threadIdx.x;
    int p0 = slotp[n * 2], p1 = slotp[n * 2 + 1];
    float w0 = wts[n * 2], w1 = wts[n * 2 + 1];
    out[n * 256 + t] = x2[n * 256 + t] + w0 * bf2f(Y[(size_t)p0 * 256 + t]) +
                       w1 * bf2f(Y[(size_t)p1 * 256 + t]);
}

extern "C" void kernel_launch(void* const* d_in, const int* in_sizes, int n_in,
                              void* d_out, int out_size, void* d_ws, size_t ws_size,
                              hipStream_t stream) {
    const float* x     = (const float*)d_in[0];
    const float* Wqkv  = (const float*)d_in[1];
    const float* Wout  = (const float*)d_in[2];
    const float* rms1w = (const float*)d_in[3];
    const float* rms2w = (const float*)d_in[4];
    const float* gateW = (const float*)d_in[5];
    const float* Wg    = (const float*)d_in[6];
    const float* Wu    = (const float*)d_in[7];
    const float* Wd    = (const float*)d_in[8];
    float* out = (float*)d_out;
    char* ws = (char*)d_ws;

    // region 0..8MB: xn1 fp32 (dead after qkv) -> xn2bf (4MB, written at rms2)
    float* xn1   = (float*)(ws + 0);
    short* xn2bf = (short*)(ws + 0);
    float* Qb  = (float*)(ws + 8388608);
    float* Kb  = (float*)(ws + 16777216);
    float* Vb  = (float*)(ws + 25165824);
    // Hbuf bf16 25.17MB over Q/K/V (dead after attn): 4194304..29360128
    short* Hbuf = (short*)(ws + 4194304);
    float* ctx = (float*)(ws + 33554432);   // dead after gemm_out
    // weight transposes in dead ctx region (written after gemm_out)
    short* WgT = (short*)(ws + 33554432);
    short* WuT = (short*)(ws + 35913728);
    short* WdT = (short*)(ws + 38273024);
    float* x2  = (float*)(ws + 41943040);
    float* xn2 = (float*)(ws + 50331648);   // dead after gate
    short* Ybuf = (short*)(ws + 50331648);  // written at moe2
    float* ct  = (float*)(ws + 58720256);
    float* st  = (float*)(ws + 58851328);
    int*   idx = (int*)(ws + 58982400);
    float* wts = (float*)(ws + 59047936);
    int* slotp = (int*)(ws + 59113472);
    int* ltok  = (int*)(ws + 59179008);
    int* cnt   = (int*)(ws + 59244544);
    int* offs  = cnt + 8;
    int* cur   = cnt + 16;
    float* imp = (float*)(cnt + 24);

    (void)hipMemsetAsync(cnt, 0, 128, stream);

    rope_tables<<<128, 256, 0, stream>>>(ct, st);
    rmsnorm_k<<<8192, 256, 0, stream>>>(x, rms1w, xn1);
    gemm_qkv<<<dim3(12, 128), 256, 0, stream>>>(xn1, Wqkv, Qb, Kb, Vb);
    rope_k<<<4096, 256, 0, stream>>>(Qb, Kb, ct, st);
    attn_k<<<dim3(32, 16), 256, 0, stream>>>(Qb, Kb, Vb, ctx);
    gemm_out<<<dim3(4, 128), 256, 0, stream>>>(ctx, Wout, x, x2);
    // ctx now dead: build bf16 transposed weights for MoE
    transcvt_k<<<dim3(24, 8, NE), 256, 0, stream>>>(Wg, WgT, 256, 768);
    transcvt_k<<<dim3(24, 8, NE), 256, 0, stream>>>(Wu, WuT, 256, 768);
    transcvt_k<<<dim3(8, 24, NE), 256, 0, stream>>>(Wd, WdT, 768, 256);
    rmsnorm_both<<<8192, 256, 0, stream>>>(x2, rms2w, xn2, xn2bf);
    gate_k<<<32, 256, 0, stream>>>(xn2, gateW, idx, wts, cnt, imp);
    prefix_k<<<1, 64, 0, stream>>>(cnt, imp, offs, cur, out + 2097152);
    scatter_k<<<32, 256, 0, stream>>>(idx, cur, ltok, slotp);
    mfma_moe1<<<dim3(12, 256, NE), 256, 0, stream>>>(xn2bf, WgT, WuT, cnt, offs, ltok, Hbuf);
    mfma_moe2<<<dim3(4, 256, NE), 256, 0, stream>>>(Hbuf, WdT, cnt, offs, Ybuf);
    combine_k<<<8192, 256, 0, stream>>>(x2, Ybuf, slotp, wts, out);
}

// Round 14
// 704.837 us; speedup vs baseline: 1.1765x; 1.1765x over previous
//
#include <hip/hip_runtime.h>
#include <hip/hip_bf16.h>
#include <math.h>

#define NE 6

typedef __bf16 bf16x8 __attribute__((ext_vector_type(8)));
typedef float f32x4 __attribute__((ext_vector_type(4)));
typedef short short8 __attribute__((ext_vector_type(8)));

// byte-offset swizzle within a [64 rows][64 k] bf16 LDS tile (row stride 128B)
#define SWZ(row, kbyte) (((row) * 128) + ((kbyte) ^ (((row) & 7) << 4)))

static __device__ __forceinline__ short f2bf(float f) {
    __hip_bfloat16 h = __float2bfloat16(f);
    return __builtin_bit_cast(short, h);
}

static __device__ __forceinline__ float bf2f(short s) {
    return __bfloat162float(__builtin_bit_cast(__hip_bfloat16, s));
}

// ---------------- RoPE tables ----------------
__global__ void rope_tables(float* __restrict__ ct, float* __restrict__ st) {
    int id = blockIdx.x * 256 + threadIdx.x;   // 2048*16
    if (id >= 2048 * 16) return;
    int s = id >> 4, f = id & 15;
    float invf = expf(-logf(10000.0f) * (float)f / 16.0f);
    float ang = (float)s * invf;
    ct[id] = cosf(ang);
    st[id] = sinf(ang);
}

// ---------------- RMSNorm (fp32 out) ----------------
__global__ void rmsnorm_k(const float* __restrict__ x, const float* __restrict__ w,
                          float* __restrict__ o) {
    __shared__ float red[256];
    int n = blockIdx.x, t = threadIdx.x;
    float v = x[n * 256 + t];
    red[t] = v * v;
    __syncthreads();
    for (int s = 128; s > 0; s >>= 1) {
        if (t < s) red[t] += red[t + s];
        __syncthreads();
    }
    float rms = rsqrtf(red[0] / 256.0f + 1e-6f);
    o[n * 256 + t] = v * rms * w[t];
}

// ---------------- RMSNorm (fp32 + bf16 out) ----------------
__global__ void rmsnorm_both(const float* __restrict__ x, const float* __restrict__ w,
                             float* __restrict__ o, short* __restrict__ obf) {
    __shared__ float red[256];
    int n = blockIdx.x, t = threadIdx.x;
    float v = x[n * 256 + t];
    red[t] = v * v;
    __syncthreads();
    for (int s = 128; s > 0; s >>= 1) {
        if (t < s) red[t] += red[t + s];
        __syncthreads();
    }
    float rms = rsqrtf(red[0] / 256.0f + 1e-6f);
    float val = v * rms * w[t];
    o[n * 256 + t] = val;
    obf[n * 256 + t] = f2bf(val);
}

// ---------------- tiled transpose + fp32->bf16: src[R][C] -> dst[C][R] ----------------
__global__ __launch_bounds__(256) void transcvt_k(const float* __restrict__ src,
                                                  short* __restrict__ dst, int R, int C) {
    __shared__ short tile[32][33];
    const float* s = src + (size_t)blockIdx.z * R * C;
    short* d = dst + (size_t)blockIdx.z * R * C;
    int t = threadIdx.x;
    int c0 = blockIdx.x * 32, r0 = blockIdx.y * 32;
    int ci = t & 31, ri0 = t >> 5;
#pragma unroll
    for (int it = 0; it < 4; it++) {
        int ri = ri0 + it * 8;
        tile[ri][ci] = f2bf(s[(size_t)(r0 + ri) * C + c0 + ci]);
    }
    __syncthreads();
#pragma unroll
    for (int it = 0; it < 4; it++) {
        int rj = ri0 + it * 8;
        d[(size_t)(c0 + rj) * R + r0 + ci] = tile[ci][rj];
    }
}

// ---------------- QKV GEMM (fp32, unchanged): scatter to Q/K/V (B,H,S,D) ----------------
__global__ __launch_bounds__(256) void gemm_qkv(const float* __restrict__ A,
                                                const float* __restrict__ W,
                                                float* __restrict__ Q, float* __restrict__ Kq,
                                                float* __restrict__ V) {
    __shared__ float As[16][64];
    __shared__ float Bs[16][64];
    int t = threadIdx.x;
    int m0 = blockIdx.y * 64, n0 = blockIdx.x * 64;
    float acc[4][4] = {};
    int am = t >> 2, ak = (t & 3) * 4;
    int bk = t >> 4, bn = (t & 15) * 4;
    int tm = (t & 15) * 4, tn = (t >> 4) * 4;
    for (int k0 = 0; k0 < 256; k0 += 16) {
        float4 av = *(const float4*)&A[(m0 + am) * 256 + k0 + ak];
        As[ak + 0][am] = av.x; As[ak + 1][am] = av.y; As[ak + 2][am] = av.z; As[ak + 3][am] = av.w;
        float4 bv = *(const float4*)&W[(k0 + bk) * 768 + n0 + bn];
        *(float4*)&Bs[bk][bn] = bv;
        __syncthreads();
#pragma unroll
        for (int kk = 0; kk < 16; kk++) {
            float4 a4 = *(float4*)&As[kk][tm];
            float4 b4 = *(float4*)&Bs[kk][tn];
            float a[4] = {a4.x, a4.y, a4.z, a4.w};
            float b[4] = {b4.x, b4.y, b4.z, b4.w};
#pragma unroll
            for (int i = 0; i < 4; i++)
#pragma unroll
                for (int j = 0; j < 4; j++) acc[i][j] += a[i] * b[j];
        }
        __syncthreads();
    }
    int part = n0 >> 8;
    float* dst = part == 0 ? Q : (part == 1 ? Kq : V);
#pragma unroll
    for (int i = 0; i < 4; i++) {
        int rowi = m0 + tm + i;
        int b = rowi >> 11, s = rowi & 2047;
#pragma unroll
        for (int j = 0; j < 4; j++) {
            int c = n0 + tn + j;
            int e = c & 255, h = e >> 5, d = e & 31;
            dst[(((size_t)(b * 8 + h)) * 2048 + s) * 32 + d] = acc[i][j];
        }
    }
}

// ---------------- RoPE in place on Q and K ----------------
__global__ void rope_k(float* __restrict__ Q, float* __restrict__ Kq,
                       const float* __restrict__ ct, const float* __restrict__ st) {
    int id = blockIdx.x * 256 + threadIdx.x;  // 32*2048*16
    if (id >= 32 * 2048 * 16) return;
    int i = id & 15;
    int s = (id >> 4) & 2047;
    int bh = id >> 15;
    int base = (bh * 2048 + s) * 32 + 2 * i;
    int j0 = (2 * i) & 15;
    float c0 = ct[s * 16 + j0], s0 = st[s * 16 + j0];
    float c1 = ct[s * 16 + j0 + 1], s1 = st[s * 16 + j0 + 1];
    float2 q = *(float2*)&Q[base];
    float2 k = *(float2*)&Kq[base];
    float2 qo, ko;
    qo.x = q.x * c0 - q.y * s0;
    qo.y = q.y * c1 + q.x * s1;
    ko.x = k.x * c0 - k.y * s0;
    ko.y = k.y * c1 + k.x * s1;
    *(float2*)&Q[base] = qo;
    *(float2*)&Kq[base] = ko;
}

// ---------------- Flash attention: 4 lanes/row, 64 rows/block, 2 keys/iter ----------------
__global__ __launch_bounds__(256) void attn_k(const float* __restrict__ Q,
                                              const float* __restrict__ Kg,
                                              const float* __restrict__ Vg,
                                              float* __restrict__ ctx) {
    __shared__ float4 Kl[64][8];
    __shared__ float4 Vl[64][8];
    int bh = blockIdx.x;
    int qt = gridDim.y - 1 - blockIdx.y;   // longest blocks launch first
    int t = threadIdx.x;
    int sub = t & 3;          // which 8-dim slice of D
    int row = qt * 64 + (t >> 2);
    const float4* Qb = (const float4*)(Q + (size_t)bh * 2048 * 32);
    const float4* Kb = (const float4*)(Kg + (size_t)bh * 2048 * 32);
    const float4* Vb = (const float4*)(Vg + (size_t)bh * 2048 * 32);
    float4 q0 = Qb[row * 8 + sub * 2];
    float4 q1 = Qb[row * 8 + sub * 2 + 1];
    float4 o0 = {}, o1 = {};
    float m = -1e30f, l = 0.f;
    const float scale = 0.17677669529663687f;  // 1/sqrt(32)
    int ntile = qt + 1;
    float4* Klf = &Kl[0][0];
    float4* Vlf = &Vl[0][0];
    for (int kt = 0; kt < ntile; kt++) {
        int kbase = kt * 64;
        Klf[t] = Kb[kbase * 8 + t];
        Klf[t + 256] = Kb[kbase * 8 + t + 256];
        Vlf[t] = Vb[kbase * 8 + t];
        Vlf[t + 256] = Vb[kbase * 8 + t + 256];
        __syncthreads();
        int jmax = row - kbase + 1;
        if (jmax > 64) jmax = 64;
        for (int j = 0; j < jmax; j += 2) {
            int jn = (j + 1) & 63;        // clamp (masked when j+1 >= jmax)
            float4 ka0 = Kl[j][sub * 2],  ka1 = Kl[j][sub * 2 + 1];
            float4 kb0 = Kl[jn][sub * 2], kb1 = Kl[jn][sub * 2 + 1];
            float sA = q0.x * ka0.x + q0.y * ka0.y + q0.z * ka0.z + q0.w * ka0.w +
                       q1.x * ka1.x + q1.y * ka1.y + q1.z * ka1.z + q1.w * ka1.w;
            float sB = q0.x * kb0.x + q0.y * kb0.y + q0.z * kb0.z + q0.w * kb0.w +
                       q1.x * kb1.x + q1.y * kb1.y + q1.z * kb1.z + q1.w * kb1.w;
            sA += __shfl_xor(sA, 1);
            sB += __shfl_xor(sB, 1);
            sA += __shfl_xor(sA, 2);
            sB += __shfl_xor(sB, 2);
            sA *= scale;
            sB *= scale;
            sB = (j + 1 < jmax) ? sB : -1e30f;
            float mn = fmaxf(m, fmaxf(sA, sB));
            float r = __expf(m - mn);        // ==1 when max unchanged; ==0 on first iter
            float p0 = __expf(sA - mn);
            float p1 = __expf(sB - mn);      // ==0 when masked
            l = l * r + p0 + p1;
            float4 va0 = Vl[j][sub * 2],  va1 = Vl[j][sub * 2 + 1];
            float4 vb0 = Vl[jn][sub * 2], vb1 = Vl[jn][sub * 2 + 1];
            o0.x = o0.x * r + p0 * va0.x + p1 * vb0.x;
            o0.y = o0.y * r + p0 * va0.y + p1 * vb0.y;
            o0.z = o0.z * r + p0 * va0.z + p1 * vb0.z;
            o0.w = o0.w * r + p0 * va0.w + p1 * vb0.w;
            o1.x = o1.x * r + p0 * va1.x + p1 * vb1.x;
            o1.y = o1.y * r + p0 * va1.y + p1 * vb1.y;
            o1.z = o1.z * r + p0 * va1.z + p1 * vb1.z;
            o1.w = o1.w * r + p0 * va1.w + p1 * vb1.w;
            m = mn;
        }
        __syncthreads();
    }
    float invl = 1.f / l;
    int b = bh >> 3, h = bh & 7;
    float4* cp = (float4*)(ctx + ((size_t)(b * 2048 + row)) * 256 + h * 32 + sub * 8);
    o0.x *= invl; o0.y *= invl; o0.z *= invl; o0.w *= invl;
    o1.x *= invl; o1.y *= invl; o1.z *= invl; o1.w *= invl;
    cp[0] = o0;
    cp[1] = o1;
}

// ---------------- out projection + residual (fp32, unchanged) ----------------
__global__ __launch_bounds__(256) void gemm_out(const float* __restrict__ A,
                                                const float* __restrict__ W,
                                                const float* __restrict__ xres,
                                                float* __restrict__ x2) {
    __shared__ float As[16][64];
    __shared__ float Bs[16][64];
    int t = threadIdx.x;
    int m0 = blockIdx.y * 64, n0 = blockIdx.x * 64;
    float acc[4][4] = {};
    int am = t >> 2, ak = (t & 3) * 4;
    int bk = t >> 4, bn = (t & 15) * 4;
    int tm = (t & 15) * 4, tn = (t >> 4) * 4;
    for (int k0 = 0; k0 < 256; k0 += 16) {
        float4 av = *(const float4*)&A[(m0 + am) * 256 + k0 + ak];
        As[ak + 0][am] = av.x; As[ak + 1][am] = av.y; As[ak + 2][am] = av.z; As[ak + 3][am] = av.w;
        float4 bv = *(const float4*)&W[(k0 + bk) * 256 + n0 + bn];
        *(float4*)&Bs[bk][bn] = bv;
        __syncthreads();
#pragma unroll
        for (int kk = 0; kk < 16; kk++) {
            float4 a4 = *(float4*)&As[kk][tm];
            float4 b4 = *(float4*)&Bs[kk][tn];
            float a[4] = {a4.x, a4.y, a4.z, a4.w};
            float b[4] = {b4.x, b4.y, b4.z, b4.w};
#pragma unroll
            for (int i = 0; i < 4; i++)
#pragma unroll
                for (int j = 0; j < 4; j++) acc[i][j] += a[i] * b[j];
        }
        __syncthreads();
    }
#pragma unroll
    for (int i = 0; i < 4; i++) {
        int rowi = m0 + tm + i;
#pragma unroll
        for (int j = 0; j < 4; j++) {
            int c = n0 + tn + j;
            x2[rowi * 256 + c] = acc[i][j] + xres[rowi * 256 + c];
        }
    }
}

// ---------------- gate: logits, softmax, top-2, importance/counts ----------------
__global__ void gate_k(const float* __restrict__ xn2, const float* __restrict__ gw,
                       int* __restrict__ idx, float* __restrict__ wts,
                       int* __restrict__ cnt, float* __restrict__ imp) {
    __shared__ float simp[NE];
    __shared__ int scnt[NE];
    int t = threadIdx.x;
    int n = blockIdx.x * 256 + t;
    if (t < NE) { simp[t] = 0.f; scnt[t] = 0; }
    __syncthreads();
    float lg[NE] = {0, 0, 0, 0, 0, 0};
    for (int k = 0; k < 256; k++) {
        float xv = xn2[n * 256 + k];
#pragma unroll
        for (int e = 0; e < NE; e++) lg[e] += xv * gw[k * NE + e];
    }
    float mx = lg[0];
#pragma unroll
    for (int e = 1; e < NE; e++) mx = fmaxf(mx, lg[e]);
    float p[NE], se = 0.f;
#pragma unroll
    for (int e = 0; e < NE; e++) { p[e] = expf(lg[e] - mx); se += p[e]; }
    float inv = 1.f / se;
#pragma unroll
    for (int e = 0; e < NE; e++) p[e] *= inv;
    int i1 = 0; float v1 = p[0];
#pragma unroll
    for (int e = 1; e < NE; e++) if (p[e] > v1) { v1 = p[e]; i1 = e; }
    int i2 = -1; float v2 = -1.f;
#pragma unroll
    for (int e = 0; e < NE; e++) if (e != i1 && p[e] > v2) { v2 = p[e]; i2 = e; }
    float e2v = expf(v2 - v1);
    float w1 = 1.f / (1.f + e2v);
    float w2 = e2v / (1.f + e2v);
    idx[n * 2] = i1; idx[n * 2 + 1] = i2;
    wts[n * 2] = w1; wts[n * 2 + 1] = w2;
#pragma unroll
    for (int e = 0; e < NE; e++) atomicAdd(&simp[e], p[e]);
    atomicAdd(&scnt[i1], 1);
    atomicAdd(&scnt[i2], 1);
    __syncthreads();
    if (t < NE) {
        atomicAdd(&imp[t], simp[t]);
        atomicAdd(&cnt[t], scnt[t]);
    }
}

// ---------------- prefix sums + aux loss ----------------
__global__ void prefix_k(const int* __restrict__ cnt, const float* __restrict__ imp,
                         int* __restrict__ offs, int* __restrict__ cur,
                         float* __restrict__ auxout) {
    if (threadIdx.x == 0) {
        int o = 0;
        float a = 0.f;
        for (int e = 0; e < NE; e++) {
            offs[e] = o;
            cur[e] = o;
            o += cnt[e];
            a += imp[e] * (float)cnt[e];
        }
        auxout[0] = 6.0f * a / (8192.0f * 8192.0f);
    }
}

// ---------------- scatter token slots into expert buckets ----------------
__global__ void scatter_k(const int* __restrict__ idx, int* __restrict__ cur,
                          int* __restrict__ ltok, int* __restrict__ slotp) {
    int n = blockIdx.x * 256 + threadIdx.x;
#pragma unroll
    for (int s = 0; s < 2; s++) {
        int e = idx[n * 2 + s];
        int pos = atomicAdd(&cur[e], 1);
        ltok[pos] = n;
        slotp[n * 2 + s] = pos;
    }
}

// ---------------- MFMA expert GEMM 1: H = silu(A@Wg)*(A@Wu), gathered rows ----------------
// A: xn2 bf16 [8192][256] gathered via ltok; B: WgT/WuT bf16 [e][768][256] (n-major)
__global__ __launch_bounds__(256) void mfma_moe1(const short* __restrict__ xnbf,
                                                 const short* __restrict__ WgT,
                                                 const short* __restrict__ WuT,
                                                 const int* __restrict__ cnt,
                                                 const int* __restrict__ offs,
                                                 const int* __restrict__ ltok,
                                                 short* __restrict__ Hbuf) {
    int e = blockIdx.z;
    int Me = cnt[e];
    int m0 = blockIdx.y * 64;
    if (m0 >= Me) return;
    int off = offs[e];
    __shared__ short As[4096], Bg[4096], Bu[4096];
    __shared__ int stok[64];
    int t = threadIdx.x;
    if (t < 64) stok[t] = (m0 + t < Me) ? ltok[off + m0 + t] : ltok[off];
    __syncthreads();
    int n0 = blockIdx.x * 64;
    const short* WgE = WgT + (size_t)e * 768 * 256;
    const short* WuE = WuT + (size_t)e * 768 * 256;
    int lane = t & 63, wid = t >> 6, wr = wid >> 1, wc = wid & 1;
    int l15 = lane & 15, lh = lane >> 4;
    int r = t >> 3, k8 = (t & 7) * 8, kb8 = (t & 7) * 16;
    char* AsC = (char*)As; char* BgC = (char*)Bg; char* BuC = (char*)Bu;
    f32x4 accg[2][2] = {}, accu[2][2] = {};
    for (int k0 = 0; k0 < 256; k0 += 64) {
        short8 av0 = *(const short8*)&xnbf[(size_t)stok[r] * 256 + k0 + k8];
        short8 av1 = *(const short8*)&xnbf[(size_t)stok[r + 32] * 256 + k0 + k8];
        short8 gv0 = *(const short8*)&WgE[(size_t)(n0 + r) * 256 + k0 + k8];
        short8 gv1 = *(const short8*)&WgE[(size_t)(n0 + r + 32) * 256 + k0 + k8];
        short8 uv0 = *(const short8*)&WuE[(size_t)(n0 + r) * 256 + k0 + k8];
        short8 uv1 = *(const short8*)&WuE[(size_t)(n0 + r + 32) * 256 + k0 + k8];
        *(short8*)(AsC + SWZ(r, kb8)) = av0;
        *(short8*)(AsC + SWZ(r + 32, kb8)) = av1;
        *(short8*)(BgC + SWZ(r, kb8)) = gv0;
        *(short8*)(BgC + SWZ(r + 32, kb8)) = gv1;
        *(short8*)(BuC + SWZ(r, kb8)) = uv0;
        *(short8*)(BuC + SWZ(r + 32, kb8)) = uv1;
        __syncthreads();
#pragma unroll
        for (int kk = 0; kk < 2; kk++) {
            int kb = kk * 64 + lh * 16;
            bf16x8 a[2], bg[2], bu[2];
#pragma unroll
            for (int i = 0; i < 2; i++) {
                a[i]  = *(const bf16x8*)(AsC + SWZ(wr * 32 + i * 16 + l15, kb));
                bg[i] = *(const bf16x8*)(BgC + SWZ(wc * 32 + i * 16 + l15, kb));
                bu[i] = *(const bf16x8*)(BuC + SWZ(wc * 32 + i * 16 + l15, kb));
            }
#pragma unroll
            for (int mi = 0; mi < 2; mi++)
#pragma unroll
                for (int ni = 0; ni < 2; ni++) {
                    accg[mi][ni] = __builtin_amdgcn_mfma_f32_16x16x32_bf16(a[mi], bg[ni], accg[mi][ni], 0, 0, 0);
                    accu[mi][ni] = __builtin_amdgcn_mfma_f32_16x16x32_bf16(a[mi], bu[ni], accu[mi][ni], 0, 0, 0);
                }
        }
        __syncthreads();
    }
#pragma unroll
    for (int mi = 0; mi < 2; mi++)
#pragma unroll
        for (int j = 0; j < 4; j++) {
            int m = m0 + wr * 32 + mi * 16 + lh * 4 + j;
            if (m < Me) {
                size_t rp = (size_t)(off + m) * 768;
#pragma unroll
                for (int ni = 0; ni < 2; ni++) {
                    int c = n0 + wc * 32 + ni * 16 + l15;
                    float g = accg[mi][ni][j], u = accu[mi][ni][j];
                    Hbuf[rp + c] = f2bf(g / (1.f + __expf(-g)) * u);
                }
            }
        }
}

// ---------------- MFMA expert GEMM 2: Y = H @ Wd ----------------
// A: Hbuf bf16 [16384][768]; B: WdT bf16 [e][256][768] (n-major)
__global__ __launch_bounds__(256) void mfma_moe2(const short* __restrict__ Hbuf,
                                                 const short* __restrict__ WdT,
                                                 const int* __restrict__ cnt,
                                                 const int* __restrict__ offs,
                                                 short* __restrict__ Y) {
    int e = blockIdx.z;
    int Me = cnt[e];
    int m0 = blockIdx.y * 64;
    if (m0 >= Me) return;
    int off = offs[e];
    __shared__ short As[4096], Bs[4096];
    int t = threadIdx.x;
    int n0 = blockIdx.x * 64;
    const short* WdE = WdT + (size_t)e * 256 * 768;
    int lane = t & 63, wid = t >> 6, wr = wid >> 1, wc = wid & 1;
    int l15 = lane & 15, lh = lane >> 4;
    int r = t >> 3, k8 = (t & 7) * 8, kb8 = (t & 7) * 16;
    int ar0 = off + m0 + r;       if (ar0 > 16383) ar0 = 16383;
    int ar1 = off + m0 + r + 32;  if (ar1 > 16383) ar1 = 16383;
    char* AsC = (char*)As; char* BsC = (char*)Bs;
    f32x4 acc[2][2] = {};
    for (int k0 = 0; k0 < 768; k0 += 64) {
        short8 av0 = *(const short8*)&Hbuf[(size_t)ar0 * 768 + k0 + k8];
        short8 av1 = *(const short8*)&Hbuf[(size_t)ar1 * 768 + k0 + k8];
        short8 bv0 = *(const short8*)&WdE[(size_t)(n0 + r) * 768 + k0 + k8];
        short8 bv1 = *(const short8*)&WdE[(size_t)(n0 + r + 32) * 768 + k0 + k8];
        *(short8*)(AsC + SWZ(r, kb8)) = av0;
        *(short8*)(AsC + SWZ(r + 32, kb8)) = av1;
        *(short8*)(BsC + SWZ(r, kb8)) = bv0;
        *(short8*)(BsC + SWZ(r + 32, kb8)) = bv1;
        __syncthreads();
#pragma unroll
        for (int kk = 0; kk < 2; kk++) {
            int kb = kk * 64 + lh * 16;
            bf16x8 a[2], b[2];
#pragma unroll
            for (int i = 0; i < 2; i++) {
                a[i] = *(const bf16x8*)(AsC + SWZ(wr * 32 + i * 16 + l15, kb));
                b[i] = *(const bf16x8*)(BsC + SWZ(wc * 32 + i * 16 + l15, kb));
            }
#pragma unroll
            for (int mi = 0; mi < 2; mi++)
#pragma unroll
                for (int ni = 0; ni < 2; ni++)
                    acc[mi][ni] = __builtin_amdgcn_mfma_f32_16x16x32_bf16(a[mi], b[ni], acc[mi][ni], 0, 0, 0);
        }
        __syncthreads();
    }
#pragma unroll
    for (int mi = 0; mi < 2; mi++)
#pragma unroll
        for (int j = 0; j < 4; j++) {
            int m = m0 + wr * 32 + mi * 16 + lh * 4 + j;
            if (m < Me) {
                size_t rp = (size_t)(off + m) * 256;
#pragma unroll
                for (int ni = 0; ni < 2; ni++) {
                    int c = n0 + wc * 32 + ni * 16 + l15;
                    Y[rp + c] = f2bf(acc[mi][ni][j]);
                }
            }
        }
}

// ---------------- final combine: out = x2 + w0*Y[p0] + w1*Y[p1] ----------------
__global__ void combine_k(const float* __restrict__ x2, const short* __restrict__ Y,
                          const int* __restrict__ slotp, const float* __restrict__ wts,
                          float* __restrict__ out) {
    int n = blockIdx.x, t = threadIdx.x;
    int p0 = slotp[n * 2], p1 = slotp[n * 2 + 1];
    float w0 = wts[n * 2], w1 = wts[n * 2 + 1];
    out[n * 256 + t] = x2[n * 256 + t] + w0 * bf2f(Y[(size_t)p0 * 256 + t]) +
                       w1 * bf2f(Y[(size_t)p1 * 256 + t]);
}

extern "C" void kernel_launch(void* const* d_in, const int* in_sizes, int n_in,
                              void* d_out, int out_size, void* d_ws, size_t ws_size,
                              hipStream_t stream) {
    const float* x     = (const float*)d_in[0];
    const float* Wqkv  = (const float*)d_in[1];
    const float* Wout  = (const float*)d_in[2];
    const float* rms1w = (const float*)d_in[3];
    const float* rms2w = (const float*)d_in[4];
    const float* gateW = (const float*)d_in[5];
    const float* Wg    = (const float*)d_in[6];
    const float* Wu    = (const float*)d_in[7];
    const float* Wd    = (const float*)d_in[8];
    float* out = (float*)d_out;
    char* ws = (char*)d_ws;

    // region 0..8MB: xn1 fp32 (dead after qkv) -> xn2bf (4MB, written at rms2)
    float* xn1   = (float*)(ws + 0);
    short* xn2bf = (short*)(ws + 0);
    float* Qb  = (float*)(ws + 8388608);
    float* Kb  = (float*)(ws + 16777216);
    float* Vb  = (float*)(ws + 25165824);
    // Hbuf bf16 25.17MB over Q/K/V (dead after attn): 4194304..29360128
    short* Hbuf = (short*)(ws + 4194304);
    float* ctx = (float*)(ws + 33554432);   // dead after gemm_out
    // weight transposes in dead ctx region (written after gemm_out)
    short* WgT = (short*)(ws + 33554432);
    short* WuT = (short*)(ws + 35913728);
    short* WdT = (short*)(ws + 38273024);
    float* x2  = (float*)(ws + 41943040);
    float* xn2 = (float*)(ws + 50331648);   // dead after gate
    short* Ybuf = (short*)(ws + 50331648);  // written at moe2
    float* ct  = (float*)(ws + 58720256);
    float* st  = (float*)(ws + 58851328);
    int*   idx = (int*)(ws + 58982400);
    float* wts = (float*)(ws + 59047936);
    int* slotp = (int*)(ws + 59113472);
    int* ltok  = (int*)(ws + 59179008);
    int* cnt   = (int*)(ws + 59244544);
    int* offs  = cnt + 8;
    int* cur   = cnt + 16;
    float* imp = (float*)(cnt + 24);

    (void)hipMemsetAsync(cnt, 0, 128, stream);

    rope_tables<<<128, 256, 0, stream>>>(ct, st);
    rmsnorm_k<<<8192, 256, 0, stream>>>(x, rms1w, xn1);
    gemm_qkv<<<dim3(12, 128), 256, 0, stream>>>(xn1, Wqkv, Qb, Kb, Vb);
    rope_k<<<4096, 256, 0, stream>>>(Qb, Kb, ct, st);
    attn_k<<<dim3(32, 32), 256, 0, stream>>>(Qb, Kb, Vb, ctx);
    gemm_out<<<dim3(4, 128), 256, 0, stream>>>(ctx, Wout, x, x2);
    // ctx now dead: build bf16 transposed weights for MoE
    transcvt_k<<<dim3(24, 8, NE), 256, 0, stream>>>(Wg, WgT, 256, 768);
    transcvt_k<<<dim3(24, 8, NE), 256, 0, stream>>>(Wu, WuT, 256, 768);
    transcvt_k<<<dim3(8, 24, NE), 256, 0, stream>>>(Wd, WdT, 768, 256);
    rmsnorm_both<<<8192, 256, 0, stream>>>(x2, rms2w, xn2, xn2bf);
    gate_k<<<32, 256, 0, stream>>>(xn2, gateW, idx, wts, cnt, imp);
    prefix_k<<<1, 64, 0, stream>>>(cnt, imp, offs, cur, out + 2097152);
    scatter_k<<<32, 256, 0, stream>>>(idx, cur, ltok, slotp);
    mfma_moe1<<<dim3(12, 256, NE), 256, 0, stream>>>(xn2bf, WgT, WuT, cnt, offs, ltok, Hbuf);
    mfma_moe2<<<dim3(4, 256, NE), 256, 0, stream>>>(Hbuf, WdT, cnt, offs, Ybuf);
    combine_k<<<8192, 256, 0, stream>>>(x2, Ybuf, slotp, wts, out);
}

// Round 15
// 675.268 us; speedup vs baseline: 1.2280x; 1.0438x over previous
//
#include <hip/hip_runtime.h>
#include <hip/hip_bf16.h>
#include <math.h>

#define NE 6

typedef __bf16 bf16x8 __attribute__((ext_vector_type(8)));
typedef float f32x4 __attribute__((ext_vector_type(4)));
typedef short short8 __attribute__((ext_vector_type(8)));

// byte-offset swizzle within a [64 rows][64 k] bf16 LDS tile (row stride 128B)
#define SWZ(row, kbyte) (((row) * 128) + ((kbyte) ^ (((row) & 7) << 4)))

static __device__ __forceinline__ short f2bf(float f) {
    __hip_bfloat16 h = __float2bfloat16(f);
    return __builtin_bit_cast(short, h);
}

static __device__ __forceinline__ float bf2f(short s) {
    return __bfloat162float(__builtin_bit_cast(__hip_bfloat16, s));
}

static __device__ __forceinline__ float dot8(float4 a0, float4 a1, float4 b0, float4 b1) {
    return a0.x * b0.x + a0.y * b0.y + a0.z * b0.z + a0.w * b0.w +
           a1.x * b1.x + a1.y * b1.y + a1.z * b1.z + a1.w * b1.w;
}

// ---------------- RoPE tables ----------------
__global__ void rope_tables(float* __restrict__ ct, float* __restrict__ st) {
    int id = blockIdx.x * 256 + threadIdx.x;   // 2048*16
    if (id >= 2048 * 16) return;
    int s = id >> 4, f = id & 15;
    float invf = expf(-logf(10000.0f) * (float)f / 16.0f);
    float ang = (float)s * invf;
    ct[id] = cosf(ang);
    st[id] = sinf(ang);
}

// ---------------- RMSNorm -> hi/lo bf16 (for bf16x3 MFMA) ----------------
__global__ void rmsnorm_hilo(const float* __restrict__ x, const float* __restrict__ w,
                             short* __restrict__ ohi, short* __restrict__ olo) {
    __shared__ float red[256];
    int n = blockIdx.x, t = threadIdx.x;
    float v = x[n * 256 + t];
    red[t] = v * v;
    __syncthreads();
    for (int s = 128; s > 0; s >>= 1) {
        if (t < s) red[t] += red[t + s];
        __syncthreads();
    }
    float rms = rsqrtf(red[0] / 256.0f + 1e-6f);
    float val = v * rms * w[t];
    short h = f2bf(val);
    ohi[n * 256 + t] = h;
    olo[n * 256 + t] = f2bf(val - bf2f(h));
}

// ---------------- RMSNorm (fp32 + bf16 out) ----------------
__global__ void rmsnorm_both(const float* __restrict__ x, const float* __restrict__ w,
                             float* __restrict__ o, short* __restrict__ obf) {
    __shared__ float red[256];
    int n = blockIdx.x, t = threadIdx.x;
    float v = x[n * 256 + t];
    red[t] = v * v;
    __syncthreads();
    for (int s = 128; s > 0; s >>= 1) {
        if (t < s) red[t] += red[t + s];
        __syncthreads();
    }
    float rms = rsqrtf(red[0] / 256.0f + 1e-6f);
    float val = v * rms * w[t];
    o[n * 256 + t] = val;
    obf[n * 256 + t] = f2bf(val);
}

// ---------------- tiled transpose + fp32->bf16: src[R][C] -> dst[C][R] ----------------
__global__ __launch_bounds__(256) void transcvt_k(const float* __restrict__ src,
                                                  short* __restrict__ dst, int R, int C) {
    __shared__ short tile[32][33];
    const float* s = src + (size_t)blockIdx.z * R * C;
    short* d = dst + (size_t)blockIdx.z * R * C;
    int t = threadIdx.x;
    int c0 = blockIdx.x * 32, r0 = blockIdx.y * 32;
    int ci = t & 31, ri0 = t >> 5;
#pragma unroll
    for (int it = 0; it < 4; it++) {
        int ri = ri0 + it * 8;
        tile[ri][ci] = f2bf(s[(size_t)(r0 + ri) * C + c0 + ci]);
    }
    __syncthreads();
#pragma unroll
    for (int it = 0; it < 4; it++) {
        int rj = ri0 + it * 8;
        d[(size_t)(c0 + rj) * R + r0 + ci] = tile[ci][rj];
    }
}

// ---------------- tiled transpose + fp32->bf16 hi/lo: src[R][C] -> dhi/dlo[C][R] ----------
__global__ __launch_bounds__(256) void transcvt2_k(const float* __restrict__ src,
                                                   short* __restrict__ dhi,
                                                   short* __restrict__ dlo, int R, int C) {
    __shared__ short th[32][33];
    __shared__ short tl[32][33];
    int t = threadIdx.x;
    int c0 = blockIdx.x * 32, r0 = blockIdx.y * 32;
    int ci = t & 31, ri0 = t >> 5;
#pragma unroll
    for (int it = 0; it < 4; it++) {
        int ri = ri0 + it * 8;
        float v = src[(size_t)(r0 + ri) * C + c0 + ci];
        short h = f2bf(v);
        th[ri][ci] = h;
        tl[ri][ci] = f2bf(v - bf2f(h));
    }
    __syncthreads();
#pragma unroll
    for (int it = 0; it < 4; it++) {
        int rj = ri0 + it * 8;
        dhi[(size_t)(c0 + rj) * R + r0 + ci] = th[ci][rj];
        dlo[(size_t)(c0 + rj) * R + r0 + ci] = tl[ci][rj];
    }
}

// ---------------- bf16x3 MFMA QKV: (8192x256)@(256x768), scatter to Q/K/V ----------------
// A hi/lo [8192][256]; B hi/lo [768][256] (n-major). acc = Ah*Bh + Ah*Bl + Al*Bh
__global__ __launch_bounds__(256) void mfma_qkv3(const short* __restrict__ Ahi,
                                                 const short* __restrict__ Alo,
                                                 const short* __restrict__ Bhi,
                                                 const short* __restrict__ Blo,
                                                 float* __restrict__ Q, float* __restrict__ Kq,
                                                 float* __restrict__ V) {
    __shared__ short sAh[4096], sAl[4096], sBh[4096], sBl[4096];
    int t = threadIdx.x;
    int m0 = blockIdx.y * 64, n0 = blockIdx.x * 64;
    int lane = t & 63, wid = t >> 6, wr = wid >> 1, wc = wid & 1;
    int l15 = lane & 15, lh = lane >> 4;
    int r = t >> 3, k8 = (t & 7) * 8, kb8 = (t & 7) * 16;
    char* Ah = (char*)sAh; char* Al = (char*)sAl; char* Bh = (char*)sBh; char* Bl = (char*)sBl;
    f32x4 acc[2][2] = {};
    for (int k0 = 0; k0 < 256; k0 += 64) {
        short8 ah0 = *(const short8*)&Ahi[(size_t)(m0 + r) * 256 + k0 + k8];
        short8 ah1 = *(const short8*)&Ahi[(size_t)(m0 + r + 32) * 256 + k0 + k8];
        short8 al0 = *(const short8*)&Alo[(size_t)(m0 + r) * 256 + k0 + k8];
        short8 al1 = *(const short8*)&Alo[(size_t)(m0 + r + 32) * 256 + k0 + k8];
        short8 bh0 = *(const short8*)&Bhi[(size_t)(n0 + r) * 256 + k0 + k8];
        short8 bh1 = *(const short8*)&Bhi[(size_t)(n0 + r + 32) * 256 + k0 + k8];
        short8 bl0 = *(const short8*)&Blo[(size_t)(n0 + r) * 256 + k0 + k8];
        short8 bl1 = *(const short8*)&Blo[(size_t)(n0 + r + 32) * 256 + k0 + k8];
        *(short8*)(Ah + SWZ(r, kb8)) = ah0;
        *(short8*)(Ah + SWZ(r + 32, kb8)) = ah1;
        *(short8*)(Al + SWZ(r, kb8)) = al0;
        *(short8*)(Al + SWZ(r + 32, kb8)) = al1;
        *(short8*)(Bh + SWZ(r, kb8)) = bh0;
        *(short8*)(Bh + SWZ(r + 32, kb8)) = bh1;
        *(short8*)(Bl + SWZ(r, kb8)) = bl0;
        *(short8*)(Bl + SWZ(r + 32, kb8)) = bl1;
        __syncthreads();
#pragma unroll
        for (int kk = 0; kk < 2; kk++) {
            int kb = kk * 64 + lh * 16;
            bf16x8 ah[2], al[2], bh[2], bl[2];
#pragma unroll
            for (int i = 0; i < 2; i++) {
                ah[i] = *(const bf16x8*)(Ah + SWZ(wr * 32 + i * 16 + l15, kb));
                al[i] = *(const bf16x8*)(Al + SWZ(wr * 32 + i * 16 + l15, kb));
                bh[i] = *(const bf16x8*)(Bh + SWZ(wc * 32 + i * 16 + l15, kb));
                bl[i] = *(const bf16x8*)(Bl + SWZ(wc * 32 + i * 16 + l15, kb));
            }
#pragma unroll
            for (int mi = 0; mi < 2; mi++)
#pragma unroll
                for (int ni = 0; ni < 2; ni++) {
                    acc[mi][ni] = __builtin_amdgcn_mfma_f32_16x16x32_bf16(ah[mi], bh[ni], acc[mi][ni], 0, 0, 0);
                    acc[mi][ni] = __builtin_amdgcn_mfma_f32_16x16x32_bf16(ah[mi], bl[ni], acc[mi][ni], 0, 0, 0);
                    acc[mi][ni] = __builtin_amdgcn_mfma_f32_16x16x32_bf16(al[mi], bh[ni], acc[mi][ni], 0, 0, 0);
                }
        }
        __syncthreads();
    }
    int part = n0 >> 8;
    float* dst = part == 0 ? Q : (part == 1 ? Kq : V);
#pragma unroll
    for (int mi = 0; mi < 2; mi++)
#pragma unroll
        for (int j = 0; j < 4; j++) {
            int m = m0 + wr * 32 + mi * 16 + lh * 4 + j;
            int b = m >> 11, s = m & 2047;
#pragma unroll
            for (int ni = 0; ni < 2; ni++) {
                int c = n0 + wc * 32 + ni * 16 + l15;
                int e = c & 255, h = e >> 5, d = e & 31;
                dst[(((size_t)(b * 8 + h)) * 2048 + s) * 32 + d] = acc[mi][ni][j];
            }
        }
}

// ---------------- bf16x3 MFMA out-proj + residual: x2 = ctx@Wout + x ----------------
__global__ __launch_bounds__(256) void mfma_out3(const short* __restrict__ Ahi,
                                                 const short* __restrict__ Alo,
                                                 const short* __restrict__ Bhi,
                                                 const short* __restrict__ Blo,
                                                 const float* __restrict__ xres,
                                                 float* __restrict__ x2) {
    __shared__ short sAh[4096], sAl[4096], sBh[4096], sBl[4096];
    int t = threadIdx.x;
    int m0 = blockIdx.y * 64, n0 = blockIdx.x * 64;
    int lane = t & 63, wid = t >> 6, wr = wid >> 1, wc = wid & 1;
    int l15 = lane & 15, lh = lane >> 4;
    int r = t >> 3, k8 = (t & 7) * 8, kb8 = (t & 7) * 16;
    char* Ah = (char*)sAh; char* Al = (char*)sAl; char* Bh = (char*)sBh; char* Bl = (char*)sBl;
    f32x4 acc[2][2] = {};
    for (int k0 = 0; k0 < 256; k0 += 64) {
        short8 ah0 = *(const short8*)&Ahi[(size_t)(m0 + r) * 256 + k0 + k8];
        short8 ah1 = *(const short8*)&Ahi[(size_t)(m0 + r + 32) * 256 + k0 + k8];
        short8 al0 = *(const short8*)&Alo[(size_t)(m0 + r) * 256 + k0 + k8];
        short8 al1 = *(const short8*)&Alo[(size_t)(m0 + r + 32) * 256 + k0 + k8];
        short8 bh0 = *(const short8*)&Bhi[(size_t)(n0 + r) * 256 + k0 + k8];
        short8 bh1 = *(const short8*)&Bhi[(size_t)(n0 + r + 32) * 256 + k0 + k8];
        short8 bl0 = *(const short8*)&Blo[(size_t)(n0 + r) * 256 + k0 + k8];
        short8 bl1 = *(const short8*)&Blo[(size_t)(n0 + r + 32) * 256 + k0 + k8];
        *(short8*)(Ah + SWZ(r, kb8)) = ah0;
        *(short8*)(Ah + SWZ(r + 32, kb8)) = ah1;
        *(short8*)(Al + SWZ(r, kb8)) = al0;
        *(short8*)(Al + SWZ(r + 32, kb8)) = al1;
        *(short8*)(Bh + SWZ(r, kb8)) = bh0;
        *(short8*)(Bh + SWZ(r + 32, kb8)) = bh1;
        *(short8*)(Bl + SWZ(r, kb8)) = bl0;
        *(short8*)(Bl + SWZ(r + 32, kb8)) = bl1;
        __syncthreads();
#pragma unroll
        for (int kk = 0; kk < 2; kk++) {
            int kb = kk * 64 + lh * 16;
            bf16x8 ah[2], al[2], bh[2], bl[2];
#pragma unroll
            for (int i = 0; i < 2; i++) {
                ah[i] = *(const bf16x8*)(Ah + SWZ(wr * 32 + i * 16 + l15, kb));
                al[i] = *(const bf16x8*)(Al + SWZ(wr * 32 + i * 16 + l15, kb));
                bh[i] = *(const bf16x8*)(Bh + SWZ(wc * 32 + i * 16 + l15, kb));
                bl[i] = *(const bf16x8*)(Bl + SWZ(wc * 32 + i * 16 + l15, kb));
            }
#pragma unroll
            for (int mi = 0; mi < 2; mi++)
#pragma unroll
                for (int ni = 0; ni < 2; ni++) {
                    acc[mi][ni] = __builtin_amdgcn_mfma_f32_16x16x32_bf16(ah[mi], bh[ni], acc[mi][ni], 0, 0, 0);
                    acc[mi][ni] = __builtin_amdgcn_mfma_f32_16x16x32_bf16(ah[mi], bl[ni], acc[mi][ni], 0, 0, 0);
                    acc[mi][ni] = __builtin_amdgcn_mfma_f32_16x16x32_bf16(al[mi], bh[ni], acc[mi][ni], 0, 0, 0);
                }
        }
        __syncthreads();
    }
#pragma unroll
    for (int mi = 0; mi < 2; mi++)
#pragma unroll
        for (int j = 0; j < 4; j++) {
            int m = m0 + wr * 32 + mi * 16 + lh * 4 + j;
#pragma unroll
            for (int ni = 0; ni < 2; ni++) {
                int c = n0 + wc * 32 + ni * 16 + l15;
                x2[(size_t)m * 256 + c] = acc[mi][ni][j] + xres[(size_t)m * 256 + c];
            }
        }
}

// ---------------- RoPE in place on Q and K ----------------
__global__ void rope_k(float* __restrict__ Q, float* __restrict__ Kq,
                       const float* __restrict__ ct, const float* __restrict__ st) {
    int id = blockIdx.x * 256 + threadIdx.x;  // 32*2048*16
    if (id >= 32 * 2048 * 16) return;
    int i = id & 15;
    int s = (id >> 4) & 2047;
    int bh = id >> 15;
    int base = (bh * 2048 + s) * 32 + 2 * i;
    int j0 = (2 * i) & 15;
    float c0 = ct[s * 16 + j0], s0 = st[s * 16 + j0];
    float c1 = ct[s * 16 + j0 + 1], s1 = st[s * 16 + j0 + 1];
    float2 q = *(float2*)&Q[base];
    float2 k = *(float2*)&Kq[base];
    float2 qo, ko;
    qo.x = q.x * c0 - q.y * s0;
    qo.y = q.y * c1 + q.x * s1;
    ko.x = k.x * c0 - k.y * s0;
    ko.y = k.y * c1 + k.x * s1;
    *(float2*)&Q[base] = qo;
    *(float2*)&Kq[base] = ko;
}

// ---------------- Flash attention: 4 lanes/row, 64 rows/block, 4 keys/iter --------------
// writes ctx as hi/lo bf16 for the bf16x3 out-projection
__global__ __launch_bounds__(256) void attn_k(const float* __restrict__ Q,
                                              const float* __restrict__ Kg,
                                              const float* __restrict__ Vg,
                                              short* __restrict__ ctxh,
                                              short* __restrict__ ctxl) {
    __shared__ float4 Kl[64][8];
    __shared__ float4 Vl[64][8];
    int bh = blockIdx.x;
    int qt = gridDim.y - 1 - blockIdx.y;   // longest blocks launch first
    int t = threadIdx.x;
    int sub = t & 3;          // which 8-dim slice of D
    int row = qt * 64 + (t >> 2);
    const float4* Qb = (const float4*)(Q + (size_t)bh * 2048 * 32);
    const float4* Kb = (const float4*)(Kg + (size_t)bh * 2048 * 32);
    const float4* Vb = (const float4*)(Vg + (size_t)bh * 2048 * 32);
    float4 q0 = Qb[row * 8 + sub * 2];
    float4 q1 = Qb[row * 8 + sub * 2 + 1];
    float4 o0 = {}, o1 = {};
    float m = -1e30f, l = 0.f;
    const float scale = 0.17677669529663687f;  // 1/sqrt(32)
    int ntile = qt + 1;
    float4* Klf = &Kl[0][0];
    float4* Vlf = &Vl[0][0];
    for (int kt = 0; kt < ntile; kt++) {
        int kbase = kt * 64;
        Klf[t] = Kb[kbase * 8 + t];
        Klf[t + 256] = Kb[kbase * 8 + t + 256];
        Vlf[t] = Vb[kbase * 8 + t];
        Vlf[t + 256] = Vb[kbase * 8 + t + 256];
        __syncthreads();
        int jmax = row - kbase + 1;
        if (jmax > 64) jmax = 64;
        for (int j = 0; j < jmax; j += 4) {
            int j1 = (j + 1) & 63, j2 = (j + 2) & 63, j3 = (j + 3) & 63;
            float s0 = dot8(q0, q1, Kl[j][sub * 2], Kl[j][sub * 2 + 1]);
            float s1 = dot8(q0, q1, Kl[j1][sub * 2], Kl[j1][sub * 2 + 1]);
            float s2 = dot8(q0, q1, Kl[j2][sub * 2], Kl[j2][sub * 2 + 1]);
            float s3 = dot8(q0, q1, Kl[j3][sub * 2], Kl[j3][sub * 2 + 1]);
            s0 += __shfl_xor(s0, 1);
            s1 += __shfl_xor(s1, 1);
            s2 += __shfl_xor(s2, 1);
            s3 += __shfl_xor(s3, 1);
            s0 += __shfl_xor(s0, 2);
            s1 += __shfl_xor(s1, 2);
            s2 += __shfl_xor(s2, 2);
            s3 += __shfl_xor(s3, 2);
            s0 *= scale;
            s1 *= scale;
            s2 *= scale;
            s3 *= scale;
            s1 = (j + 1 < jmax) ? s1 : -1e30f;
            s2 = (j + 2 < jmax) ? s2 : -1e30f;
            s3 = (j + 3 < jmax) ? s3 : -1e30f;
            float mn = fmaxf(m, fmaxf(fmaxf(s0, s1), fmaxf(s2, s3)));
            float rr = __expf(m - mn);
            float p0 = __expf(s0 - mn);
            float p1 = __expf(s1 - mn);
            float p2 = __expf(s2 - mn);
            float p3 = __expf(s3 - mn);
            l = l * rr + ((p0 + p1) + (p2 + p3));
            float4 v00 = Vl[j][sub * 2],  v01 = Vl[j][sub * 2 + 1];
            float4 v10 = Vl[j1][sub * 2], v11 = Vl[j1][sub * 2 + 1];
            float4 v20 = Vl[j2][sub * 2], v21 = Vl[j2][sub * 2 + 1];
            float4 v30 = Vl[j3][sub * 2], v31 = Vl[j3][sub * 2 + 1];
            o0.x = o0.x * rr + p0 * v00.x + p1 * v10.x + p2 * v20.x + p3 * v30.x;
            o0.y = o0.y * rr + p0 * v00.y + p1 * v10.y + p2 * v20.y + p3 * v30.y;
            o0.z = o0.z * rr + p0 * v00.z + p1 * v10.z + p2 * v20.z + p3 * v30.z;
            o0.w = o0.w * rr + p0 * v00.w + p1 * v10.w + p2 * v20.w + p3 * v30.w;
            o1.x = o1.x * rr + p0 * v01.x + p1 * v11.x + p2 * v21.x + p3 * v31.x;
            o1.y = o1.y * rr + p0 * v01.y + p1 * v11.y + p2 * v21.y + p3 * v31.y;
            o1.z = o1.z * rr + p0 * v01.z + p1 * v11.z + p2 * v21.z + p3 * v31.z;
            o1.w = o1.w * rr + p0 * v01.w + p1 * v11.w + p2 * v21.w + p3 * v31.w;
            m = mn;
        }
        __syncthreads();
    }
    float invl = 1.f / l;
    int b = bh >> 3, h = bh & 7;
    float vals[8] = {o0.x * invl, o0.y * invl, o0.z * invl, o0.w * invl,
                     o1.x * invl, o1.y * invl, o1.z * invl, o1.w * invl};
    short8 hs, ls;
#pragma unroll
    for (int i = 0; i < 8; i++) {
        short hv = f2bf(vals[i]);
        hs[i] = hv;
        ls[i] = f2bf(vals[i] - bf2f(hv));
    }
    size_t base = ((size_t)(b * 2048 + row)) * 256 + h * 32 + sub * 8;
    *(short8*)&ctxh[base] = hs;
    *(short8*)&ctxl[base] = ls;
}

// ---------------- gate: logits, softmax, top-2, importance/counts ----------------
__global__ void gate_k(const float* __restrict__ xn2, const float* __restrict__ gw,
                       int* __restrict__ idx, float* __restrict__ wts,
                       int* __restrict__ cnt, float* __restrict__ imp) {
    __shared__ float simp[NE];
    __shared__ int scnt[NE];
    int t = threadIdx.x;
    int n = blockIdx.x * 256 + t;
    if (t < NE) { simp[t] = 0.f; scnt[t] = 0; }
    __syncthreads();
    float lg[NE] = {0, 0, 0, 0, 0, 0};
    for (int k = 0; k < 256; k++) {
        float xv = xn2[n * 256 + k];
#pragma unroll
        for (int e = 0; e < NE; e++) lg[e] += xv * gw[k * NE + e];
    }
    float mx = lg[0];
#pragma unroll
    for (int e = 1; e < NE; e++) mx = fmaxf(mx, lg[e]);
    float p[NE], se = 0.f;
#pragma unroll
    for (int e = 0; e < NE; e++) { p[e] = expf(lg[e] - mx); se += p[e]; }
    float inv = 1.f / se;
#pragma unroll
    for (int e = 0; e < NE; e++) p[e] *= inv;
    int i1 = 0; float v1 = p[0];
#pragma unroll
    for (int e = 1; e < NE; e++) if (p[e] > v1) { v1 = p[e]; i1 = e; }
    int i2 = -1; float v2 = -1.f;
#pragma unroll
    for (int e = 0; e < NE; e++) if (e != i1 && p[e] > v2) { v2 = p[e]; i2 = e; }
    float e2v = expf(v2 - v1);
    float w1 = 1.f / (1.f + e2v);
    float w2 = e2v / (1.f + e2v);
    idx[n * 2] = i1; idx[n * 2 + 1] = i2;
    wts[n * 2] = w1; wts[n * 2 + 1] = w2;
#pragma unroll
    for (int e = 0; e < NE; e++) atomicAdd(&simp[e], p[e]);
    atomicAdd(&scnt[i1], 1);
    atomicAdd(&scnt[i2], 1);
    __syncthreads();
    if (t < NE) {
        atomicAdd(&imp[t], simp[t]);
        atomicAdd(&cnt[t], scnt[t]);
    }
}

// ---------------- prefix sums + aux loss ----------------
__global__ void prefix_k(const int* __restrict__ cnt, const float* __restrict__ imp,
                         int* __restrict__ offs, int* __restrict__ cur,
                         float* __restrict__ auxout) {
    if (threadIdx.x == 0) {
        int o = 0;
        float a = 0.f;
        for (int e = 0; e < NE; e++) {
            offs[e] = o;
            cur[e] = o;
            o += cnt[e];
            a += imp[e] * (float)cnt[e];
        }
        auxout[0] = 6.0f * a / (8192.0f * 8192.0f);
    }
}

// ---------------- scatter token slots into expert buckets ----------------
__global__ void scatter_k(const int* __restrict__ idx, int* __restrict__ cur,
                          int* __restrict__ ltok, int* __restrict__ slotp) {
    int n = blockIdx.x * 256 + threadIdx.x;
#pragma unroll
    for (int s = 0; s < 2; s++) {
        int e = idx[n * 2 + s];
        int pos = atomicAdd(&cur[e], 1);
        ltok[pos] = n;
        slotp[n * 2 + s] = pos;
    }
}

// ---------------- MFMA expert GEMM 1: H = silu(A@Wg)*(A@Wu), gathered rows ----------------
__global__ __launch_bounds__(256) void mfma_moe1(const short* __restrict__ xnbf,
                                                 const short* __restrict__ WgT,
                                                 const short* __restrict__ WuT,
                                                 const int* __restrict__ cnt,
                                                 const int* __restrict__ offs,
                                                 const int* __restrict__ ltok,
                                                 short* __restrict__ Hbuf) {
    int e = blockIdx.z;
    int Me = cnt[e];
    int m0 = blockIdx.y * 64;
    if (m0 >= Me) return;
    int off = offs[e];
    __shared__ short As[4096], Bg[4096], Bu[4096];
    __shared__ int stok[64];
    int t = threadIdx.x;
    if (t < 64) stok[t] = (m0 + t < Me) ? ltok[off + m0 + t] : ltok[off];
    __syncthreads();
    int n0 = blockIdx.x * 64;
    const short* WgE = WgT + (size_t)e * 768 * 256;
    const short* WuE = WuT + (size_t)e * 768 * 256;
    int lane = t & 63, wid = t >> 6, wr = wid >> 1, wc = wid & 1;
    int l15 = lane & 15, lh = lane >> 4;
    int r = t >> 3, k8 = (t & 7) * 8, kb8 = (t & 7) * 16;
    char* AsC = (char*)As; char* BgC = (char*)Bg; char* BuC = (char*)Bu;
    f32x4 accg[2][2] = {}, accu[2][2] = {};
    for (int k0 = 0; k0 < 256; k0 += 64) {
        short8 av0 = *(const short8*)&xnbf[(size_t)stok[r] * 256 + k0 + k8];
        short8 av1 = *(const short8*)&xnbf[(size_t)stok[r + 32] * 256 + k0 + k8];
        short8 gv0 = *(const short8*)&WgE[(size_t)(n0 + r) * 256 + k0 + k8];
        short8 gv1 = *(const short8*)&WgE[(size_t)(n0 + r + 32) * 256 + k0 + k8];
        short8 uv0 = *(const short8*)&WuE[(size_t)(n0 + r) * 256 + k0 + k8];
        short8 uv1 = *(const short8*)&WuE[(size_t)(n0 + r + 32) * 256 + k0 + k8];
        *(short8*)(AsC + SWZ(r, kb8)) = av0;
        *(short8*)(AsC + SWZ(r + 32, kb8)) = av1;
        *(short8*)(BgC + SWZ(r, kb8)) = gv0;
        *(short8*)(BgC + SWZ(r + 32, kb8)) = gv1;
        *(short8*)(BuC + SWZ(r, kb8)) = uv0;
        *(short8*)(BuC + SWZ(r + 32, kb8)) = uv1;
        __syncthreads();
#pragma unroll
        for (int kk = 0; kk < 2; kk++) {
            int kb = kk * 64 + lh * 16;
            bf16x8 a[2], bg[2], bu[2];
#pragma unroll
            for (int i = 0; i < 2; i++) {
                a[i]  = *(const bf16x8*)(AsC + SWZ(wr * 32 + i * 16 + l15, kb));
                bg[i] = *(const bf16x8*)(BgC + SWZ(wc * 32 + i * 16 + l15, kb));
                bu[i] = *(const bf16x8*)(BuC + SWZ(wc * 32 + i * 16 + l15, kb));
            }
#pragma unroll
            for (int mi = 0; mi < 2; mi++)
#pragma unroll
                for (int ni = 0; ni < 2; ni++) {
                    accg[mi][ni] = __builtin_amdgcn_mfma_f32_16x16x32_bf16(a[mi], bg[ni], accg[mi][ni], 0, 0, 0);
                    accu[mi][ni] = __builtin_amdgcn_mfma_f32_16x16x32_bf16(a[mi], bu[ni], accu[mi][ni], 0, 0, 0);
                }
        }
        __syncthreads();
    }
#pragma unroll
    for (int mi = 0; mi < 2; mi++)
#pragma unroll
        for (int j = 0; j < 4; j++) {
            int m = m0 + wr * 32 + mi * 16 + lh * 4 + j;
            if (m < Me) {
                size_t rp = (size_t)(off + m) * 768;
#pragma unroll
                for (int ni = 0; ni < 2; ni++) {
                    int c = n0 + wc * 32 + ni * 16 + l15;
                    float g = accg[mi][ni][j], u = accu[mi][ni][j];
                    Hbuf[rp + c] = f2bf(g / (1.f + __expf(-g)) * u);
                }
            }
        }
}

// ---------------- MFMA expert GEMM 2: Y = H @ Wd ----------------
__global__ __launch_bounds__(256) void mfma_moe2(const short* __restrict__ Hbuf,
                                                 const short* __restrict__ WdT,
                                                 const int* __restrict__ cnt,
                                                 const int* __restrict__ offs,
                                                 short* __restrict__ Y) {
    int e = blockIdx.z;
    int Me = cnt[e];
    int m0 = blockIdx.y * 64;
    if (m0 >= Me) return;
    int off = offs[e];
    __shared__ short As[4096], Bs[4096];
    int t = threadIdx.x;
    int n0 = blockIdx.x * 64;
    const short* WdE = WdT + (size_t)e * 256 * 768;
    int lane = t & 63, wid = t >> 6, wr = wid >> 1, wc = wid & 1;
    int l15 = lane & 15, lh = lane >> 4;
    int r = t >> 3, k8 = (t & 7) * 8, kb8 = (t & 7) * 16;
    int ar0 = off + m0 + r;       if (ar0 > 16383) ar0 = 16383;
    int ar1 = off + m0 + r + 32;  if (ar1 > 16383) ar1 = 16383;
    char* AsC = (char*)As; char* BsC = (char*)Bs;
    f32x4 acc[2][2] = {};
    for (int k0 = 0; k0 < 768; k0 += 64) {
        short8 av0 = *(const short8*)&Hbuf[(size_t)ar0 * 768 + k0 + k8];
        short8 av1 = *(const short8*)&Hbuf[(size_t)ar1 * 768 + k0 + k8];
        short8 bv0 = *(const short8*)&WdE[(size_t)(n0 + r) * 768 + k0 + k8];
        short8 bv1 = *(const short8*)&WdE[(size_t)(n0 + r + 32) * 768 + k0 + k8];
        *(short8*)(AsC + SWZ(r, kb8)) = av0;
        *(short8*)(AsC + SWZ(r + 32, kb8)) = av1;
        *(short8*)(BsC + SWZ(r, kb8)) = bv0;
        *(short8*)(BsC + SWZ(r + 32, kb8)) = bv1;
        __syncthreads();
#pragma unroll
        for (int kk = 0; kk < 2; kk++) {
            int kb = kk * 64 + lh * 16;
            bf16x8 a[2], b[2];
#pragma unroll
            for (int i = 0; i < 2; i++) {
                a[i] = *(const bf16x8*)(AsC + SWZ(wr * 32 + i * 16 + l15, kb));
                b[i] = *(const bf16x8*)(BsC + SWZ(wc * 32 + i * 16 + l15, kb));
            }
#pragma unroll
            for (int mi = 0; mi < 2; mi++)
#pragma unroll
                for (int ni = 0; ni < 2; ni++)
                    acc[mi][ni] = __builtin_amdgcn_mfma_f32_16x16x32_bf16(a[mi], b[ni], acc[mi][ni], 0, 0, 0);
        }
        __syncthreads();
    }
#pragma unroll
    for (int mi = 0; mi < 2; mi++)
#pragma unroll
        for (int j = 0; j < 4; j++) {
            int m = m0 + wr * 32 + mi * 16 + lh * 4 + j;
            if (m < Me) {
                size_t rp = (size_t)(off + m) * 256;
#pragma unroll
                for (int ni = 0; ni < 2; ni++) {
                    int c = n0 + wc * 32 + ni * 16 + l15;
                    Y[rp + c] = f2bf(acc[mi][ni][j]);
                }
            }
        }
}

// ---------------- final combine: out = x2 + w0*Y[p0] + w1*Y[p1] ----------------
__global__ void combine_k(const float* __restrict__ x2, const short* __restrict__ Y,
                          const int* __restrict__ slotp, const float* __restrict__ wts,
                          float* __restrict__ out) {
    int n = blockIdx.x, t = threadIdx.x;
    int p0 = slotp[n * 2], p1 = slotp[n * 2 + 1];
    float w0 = wts[n * 2], w1 = wts[n * 2 + 1];
    out[n * 256 + t] = x2[n * 256 + t] + w0 * bf2f(Y[(size_t)p0 * 256 + t]) +
                       w1 * bf2f(Y[(size_t)p1 * 256 + t]);
}

extern "C" void kernel_launch(void* const* d_in, const int* in_sizes, int n_in,
                              void* d_out, int out_size, void* d_ws, size_t ws_size,
                              hipStream_t stream) {
    const float* x     = (const float*)d_in[0];
    const float* Wqkv  = (const float*)d_in[1];
    const float* Wout  = (const float*)d_in[2];
    const float* rms1w = (const float*)d_in[3];
    const float* rms2w = (const float*)d_in[4];
    const float* gateW = (const float*)d_in[5];
    const float* Wg    = (const float*)d_in[6];
    const float* Wu    = (const float*)d_in[7];
    const float* Wd    = (const float*)d_in[8];
    float* out = (float*)d_out;
    char* ws = (char*)d_ws;

    // 0..8MB: xn1 hi/lo bf16 (dead after qkv) -> xn2bf (4MB) + Hbuf start
    short* xn1hi = (short*)(ws + 0);
    short* xn1lo = (short*)(ws + 4194304);
    short* xn2bf = (short*)(ws + 0);
    float* Qb  = (float*)(ws + 8388608);
    float* Kb  = (float*)(ws + 16777216);
    float* Vb  = (float*)(ws + 25165824);
    short* Hbuf = (short*)(ws + 4194304);   // 25.2MB over xn1lo/Q/K/V (dead after attn)
    // ctx hi/lo bf16 (dead after mfma_out3), then moe weight transposes
    short* ctxh = (short*)(ws + 33554432);
    short* ctxl = (short*)(ws + 37748736);
    short* WgT = (short*)(ws + 33554432);
    short* WuT = (short*)(ws + 35913728);
    short* WdT = (short*)(ws + 38273024);
    float* x2  = (float*)(ws + 41943040);
    // 50331648..58720256: qkv/out weight transposes (early) -> xn2 fp32 -> Ybuf
    float* xn2 = (float*)(ws + 50331648);
    short* WqkvThi = (short*)(ws + 50331648);
    short* WqkvTlo = (short*)(ws + 50724864);
    short* WoutThi = (short*)(ws + 51118080);
    short* WoutTlo = (short*)(ws + 51249152);
    short* Ybuf = (short*)(ws + 50331648);
    float* ct  = (float*)(ws + 58720256);
    float* st  = (float*)(ws + 58851328);
    int*   idx = (int*)(ws + 58982400);
    float* wts = (float*)(ws + 59047936);
    int* slotp = (int*)(ws + 59113472);
    int* ltok  = (int*)(ws + 59179008);
    int* cnt   = (int*)(ws + 59244544);
    int* offs  = cnt + 8;
    int* cur   = cnt + 16;
    float* imp = (float*)(cnt + 24);

    (void)hipMemsetAsync(cnt, 0, 128, stream);

    rope_tables<<<128, 256, 0, stream>>>(ct, st);
    transcvt2_k<<<dim3(24, 8), 256, 0, stream>>>(Wqkv, WqkvThi, WqkvTlo, 256, 768);
    transcvt2_k<<<dim3(8, 8), 256, 0, stream>>>(Wout, WoutThi, WoutTlo, 256, 256);
    rmsnorm_hilo<<<8192, 256, 0, stream>>>(x, rms1w, xn1hi, xn1lo);
    mfma_qkv3<<<dim3(12, 128), 256, 0, stream>>>(xn1hi, xn1lo, WqkvThi, WqkvTlo, Qb, Kb, Vb);
    rope_k<<<4096, 256, 0, stream>>>(Qb, Kb, ct, st);
    attn_k<<<dim3(32, 32), 256, 0, stream>>>(Qb, Kb, Vb, ctxh, ctxl);
    mfma_out3<<<dim3(4, 128), 256, 0, stream>>>(ctxh, ctxl, WoutThi, WoutTlo, x, x2);
    // ctx now dead: build bf16 transposed weights for MoE
    transcvt_k<<<dim3(24, 8, NE), 256, 0, stream>>>(Wg, WgT, 256, 768);
    transcvt_k<<<dim3(24, 8, NE), 256, 0, stream>>>(Wu, WuT, 256, 768);
    transcvt_k<<<dim3(8, 24, NE), 256, 0, stream>>>(Wd, WdT, 768, 256);
    rmsnorm_both<<<8192, 256, 0, stream>>>(x2, rms2w, xn2, xn2bf);
    gate_k<<<32, 256, 0, stream>>>(xn2, gateW, idx, wts, cnt, imp);
    prefix_k<<<1, 64, 0, stream>>>(cnt, imp, offs, cur, out + 2097152);
    scatter_k<<<32, 256, 0, stream>>>(idx, cur, ltok, slotp);
    mfma_moe1<<<dim3(12, 256, NE), 256, 0, stream>>>(xn2bf, WgT, WuT, cnt, offs, ltok, Hbuf);
    mfma_moe2<<<dim3(4, 256, NE), 256, 0, stream>>>(Hbuf, WdT, cnt, offs, Ybuf);
    combine_k<<<8192, 256, 0, stream>>>(x2, Ybuf, slotp, wts, out);
}